// Round 6
// baseline (323.817 us; speedup 1.0000x reference)
//
#include <hip/hip_runtime.h>
#include <hip/hip_bf16.h>

#define B_   64
#define N_   512
#define M_   512
#define Dm_  64
#define BIGF 1e30f
// gamma = 0.1; scaled units R' = R / (gamma*ln2):
//   r' = d' + mn' - log2(2^(mn'-a') + 2^(mn'-b') + 2^(mn'-c'))
#define SINV 14.426950408889634f    // 1/(gamma*ln2)
#define LAG  16                     // inter-wave lag = barrier period
#define RING 64                     // ring slots per wave boundary
#define SPAD 1136                   // padded step count (= 71*16 >= 1135)

// Raw transcendental instructions (bypass OCML wrapper fixup code).
#if __has_builtin(__builtin_amdgcn_exp2f)
#define EXP2F(x) __builtin_amdgcn_exp2f(x)
#else
#define EXP2F(x) exp2f(x)
#endif
#if __has_builtin(__builtin_amdgcn_logf)
#define LOG2F(x) __builtin_amdgcn_logf(x)   // v_log_f32 computes log2
#else
#define LOG2F(x) __log2f(x)
#endif

// ---------------------------------------------------------------------------
// Kernel A: skewed bf16 distance matrix.
//   Ds[b][s][t] = bf16( SINV * ||x[b,t,:] - y[b,s-skew(t),:]||^2 ),
//   skew(t) = t + (t>>6)*LAG.  At DP step s all 512 lanes read row s
//   contiguously -> perfectly coalesced loads in the latency-bound DP.
// ---------------------------------------------------------------------------
__global__ __launch_bounds__(256) void dtw_dist_skew(const float* __restrict__ x,
                                                     const float* __restrict__ y,
                                                     __hip_bfloat16* __restrict__ Ds) {
  __shared__ float xs[128][65];
  __shared__ float ys[128][65];
  const int b  = blockIdx.z;
  const int i0 = blockIdx.y * 128;
  const int j0 = blockIdx.x * 128;
  const int tid = threadIdx.x;

  const float* xb = x + ((size_t)b * N_ + i0) * Dm_;
  const float* yb = y + ((size_t)b * M_ + j0) * Dm_;
#pragma unroll
  for (int r = 0; r < 8; ++r) {
    int v4 = tid + r * 256;
    int row = v4 >> 4, c4 = (v4 & 15) * 4;
    float4 xv = *(const float4*)(xb + (size_t)row * Dm_ + c4);
    float4 yv = *(const float4*)(yb + (size_t)row * Dm_ + c4);
    xs[row][c4 + 0] = xv.x; xs[row][c4 + 1] = xv.y;
    xs[row][c4 + 2] = xv.z; xs[row][c4 + 3] = xv.w;
    ys[row][c4 + 0] = yv.x; ys[row][c4 + 1] = yv.y;
    ys[row][c4 + 2] = yv.z; ys[row][c4 + 3] = yv.w;
  }
  __syncthreads();

  const int ty = tid >> 4, tx = tid & 15;
  float acc[8][8];
#pragma unroll
  for (int e = 0; e < 8; ++e)
#pragma unroll
    for (int f = 0; f < 8; ++f) acc[e][f] = 0.f;

#pragma unroll 4
  for (int k = 0; k < Dm_; ++k) {
    float xa[8], yv[8];
#pragma unroll
    for (int e = 0; e < 8; ++e) xa[e] = xs[ty * 8 + e][k];
#pragma unroll
    for (int f = 0; f < 8; ++f) yv[f] = ys[tx * 8 + f][k];
#pragma unroll
    for (int e = 0; e < 8; ++e)
#pragma unroll
      for (int f = 0; f < 8; ++f) {
        float t = xa[e] - yv[f];
        acc[e][f] = fmaf(t, t, acc[e][f]);
      }
  }

  __hip_bfloat16* base = Ds + (size_t)b * SPAD * N_;
#pragma unroll
  for (int e = 0; e < 8; ++e) {
    const int t  = i0 + ty * 8 + e;
    const int sk = t + (t >> 6) * LAG;
#pragma unroll
    for (int f = 0; f < 8; ++f) {
      const int s = j0 + tx * 8 + f + sk;          // global DP step index
      base[(size_t)s * N_ + t] = __float2bfloat16(acc[e][f] * SINV);
    }
  }
}

// ---------------------------------------------------------------------------
// Kernel B: skewed-pipeline DP, TWO batches per block (independent chains
// interleaved to fill the stall cycles). Lane t owns row i=t+1 of each
// batch; step s computes column j = s - skew + 1 (skew = t + wave*LAG).
//   A = R'[i-1][j]   : lane t-1's r @ s-1 via DPP wave_shr:1
//   B = R'[i][j-1]   : own previous value (register)
//   C = R'[i-1][j-1] : lane t-1's r @ s-2 (previous A)
// Publish: branchless — cndmask'd address: lane63/waves0-6 -> ring slot,
// all other lanes -> a private per-lane trash slot (distinct addrs, 2-way
// bank aliasing = free; NOT R3's same-address storm).
// ---------------------------------------------------------------------------
__global__ __launch_bounds__(512, 1) void dtw_dp3(const ushort* __restrict__ Ds,
                                                  float* __restrict__ wv) {
  const int q    = blockIdx.x;        // 0..31
  const int b0   = q * 2;
  const int t    = threadIdx.x;       // 0..511
  const int w    = t >> 6;            // wave 0..7
  const int lane = t & 63;
  const int skew = t + w * LAG;

  // layout: [ring batch0: 8*RING][ring batch1: 8*RING][trash: 512]
  __shared__ float shm[2 * 8 * RING + 512];
  for (int i2 = t; i2 < 2 * 8 * RING; i2 += 512) shm[i2] = BIGF;
  __syncthreads();

  const ushort* col0 = Ds + (size_t)b0 * SPAD * N_ + t;        // column t
  const ushort* col1 = col0 + (size_t)SPAD * N_;
  const int rd0 = ((w + 7) & 7) * RING;            // read row w-1 (w=0 -> 7: BIGF)
  const int rd1 = 8 * RING + rd0;
  const bool pub = (lane == 63) && (w < 7);
  const int wr0 = w * RING;
  const int wr1 = 8 * RING + wr0;
  const int trash_idx = 2 * 8 * RING + t;

  float A0 = (t == 0) ? 0.0f : BIGF, B0v = BIGF, r0 = BIGF;
  float A1 = (t == 0) ? 0.0f : BIGF, B1v = BIGF, r1 = BIGF;

  float dc0[LAG], dc1[LAG];
  {
    ushort a0[LAG], a1[LAG];
#pragma unroll
    for (int k = 0; k < LAG; ++k) {
      a0[k] = col0[(size_t)k * N_];
      a1[k] = col1[(size_t)k * N_];
    }
#pragma unroll
    for (int k = 0; k < LAG; ++k) {
      dc0[k] = __uint_as_float((uint)a0[k] << 16);
      dc1[k] = __uint_as_float((uint)a1[k] << 16);
    }
  }

#define DP_STEP(AX, BX, RX, RVX, DCX, WRB)                                   \
  {                                                                          \
    const int nbi = __builtin_amdgcn_update_dpp(__float_as_int(RVX),         \
                    __float_as_int(RX), 0x138 /*wave_shr:1*/, 0xF, 0xF, false);\
    const float nb = __int_as_float(nbi);                                    \
    const float Cv = AX; AX = nb;                                            \
    const float mn = fminf(fminf(AX, BX), Cv);                               \
    const float ev = (EXP2F(mn - AX) + EXP2F(mn - BX)) + EXP2F(mn - Cv);     \
    const float rr = (DCX + mn) - LOG2F(ev);                                 \
    RX = active ? rr : BIGF;                                                 \
    BX = active ? rr : BX;                                                   \
    shm[pub ? (WRB + slot) : trash_idx] = RX;                                \
  }

  const int NBLK = SPAD / LAG;   // 71
  for (int blk = 0; blk < NBLK; ++blk) {
    const int s0 = blk * LAG;

    // issue next block's coalesced row loads, pinned before the compute
    ushort nx0[LAG], nx1[LAG];
#pragma unroll
    for (int k = 0; k < LAG; ++k) {
      int sl = s0 + LAG + k; sl = sl > SPAD - 1 ? SPAD - 1 : sl;
      nx0[k] = col0[(size_t)sl * N_];
      nx1[k] = col1[(size_t)sl * N_];
    }
    __builtin_amdgcn_sched_barrier(0);

    // ring values (uniform-address LDS broadcast), one epoch old
    float rv0[LAG], rv1[LAG];
#pragma unroll
    for (int k = 0; k < LAG; ++k) {
      const int sl2 = (s0 + k - LAG - 1) & (RING - 1);
      rv0[k] = shm[rd0 + sl2];
      rv1[k] = shm[rd1 + sl2];
    }
    __builtin_amdgcn_sched_barrier(0);

#pragma unroll
    for (int k = 0; k < LAG; ++k) {
      const int s = s0 + k;
      const int n = s - skew;
      const bool active = (n >= 0) && (n < M_);
      const int slot = s & (RING - 1);
      DP_STEP(A0, B0v, r0, rv0[k], dc0[k], wr0)
      DP_STEP(A1, B1v, r1, rv1[k], dc1[k], wr1)
    }
    __syncthreads();   // drains nx loads (issued ~16 steps of compute ago)

#pragma unroll
    for (int k = 0; k < LAG; ++k) {
      dc0[k] = __uint_as_float((uint)nx0[k] << 16);
      dc1[k] = __uint_as_float((uint)nx1[k] << 16);
    }
  }
#undef DP_STEP

  if (t == N_ - 1) {
    wv[b0]     = EXP2F(-0.1f * B0v);   // w = exp(-R) = 2^(-gamma*R')
    wv[b0 + 1] = EXP2F(-0.1f * B1v);
  }
}

// ---------------------------------------------------------------------------
// Kernel C: out = x * w[b], full-grid elementwise (float4).
// ---------------------------------------------------------------------------
__global__ __launch_bounds__(256) void dtw_mul_kernel(const float* __restrict__ x,
                                                      const float* __restrict__ wv,
                                                      float* __restrict__ out) {
  const int idx = blockIdx.x * 256 + threadIdx.x;   // float4 index
  const int b = idx >> 13;                          // 8192 float4 per batch
  const float w = wv[b];
  float4 v = ((const float4*)x)[idx];
  v.x *= w; v.y *= w; v.z *= w; v.w *= w;
  ((float4*)out)[idx] = v;
}

// ---------------------------------------------------------------------------
// Fallback (no workspace): barrier-per-step fused DP. Slow but correct.
// ---------------------------------------------------------------------------
__global__ __launch_bounds__(512) void dtw_dp_fused(const float* __restrict__ x,
                                                    const float* __restrict__ y,
                                                    float* __restrict__ out) {
  __shared__ float v[3][516];
  const int b = blockIdx.x;
  const int t = threadIdx.x;
  const int i = t + 1;
  if (t == 0) { v[0][0] = 0.f; v[1][0] = BIGF; v[2][0] = BIGF; }
  v[0][i] = BIGF;
  v[1][i] = BIGF;
  float xr[Dm_];
  const float* xrow = x + ((size_t)b * N_ + t) * Dm_;
#pragma unroll
  for (int k = 0; k < Dm_; ++k) xr[k] = xrow[k];
  __syncthreads();
  int cur = 2, m1 = 1, m2 = 0;
  const float GLN2 = 0.069314718055994531f;
  for (int p = 2; p <= N_ + M_; ++p) {
    const int j = p - i;
    const bool valid = (j >= 1) && (j <= M_);
    float d = 0.f;
    if (valid) {
      const float* yr = y + ((size_t)b * M_ + (j - 1)) * Dm_;
      float a = 0.f;
#pragma unroll
      for (int k = 0; k < Dm_; ++k) { float u = xr[k] - yr[k]; a = fmaf(u, u, a); }
      d = a;
    }
    const float a  = v[m1][i - 1];
    const float bb = v[m1][i];
    const float c  = v[m2][i - 1];
    const float mn = fminf(fminf(a, bb), c);
    const float s = exp2f((mn - a) * SINV) + exp2f((mn - bb) * SINV) +
                    exp2f((mn - c) * SINV);
    const float rr = valid ? (d + mn - GLN2 * log2f(s)) : BIGF;
    v[cur][i] = rr;
    if (t == 0) v[cur][0] = BIGF;
    __syncthreads();
    const int tmp = m2; m2 = m1; m1 = cur; cur = tmp;
  }
  const float dist = v[(N_ + M_) % 3][N_];
  const float wsc = expf(-dist);
  const float* xb = x + (size_t)b * N_ * Dm_;
  float* ob = out + (size_t)b * N_ * Dm_;
#pragma unroll
  for (int e = 0; e < (N_ * Dm_) / 512; ++e) {
    const int idx = e * 512 + t;
    ob[idx] = xb[idx] * wsc;
  }
}

// ---------------------------------------------------------------------------
extern "C" void kernel_launch(void* const* d_in, const int* in_sizes, int n_in,
                              void* d_out, int out_size, void* d_ws, size_t ws_size,
                              hipStream_t stream) {
  const float* x = (const float*)d_in[0];
  const float* y = (const float*)d_in[1];
  float* out = (float*)d_out;

  const size_t needS = (size_t)B_ * SPAD * N_ * 2;   // 74,448,896 B
  const int mul_grid = (B_ * N_ * Dm_ / 4) / 256;    // 2048

  if (ws_size >= needS + 4096) {
    __hip_bfloat16* Dsb = (__hip_bfloat16*)d_ws;
    float* wvp = (float*)((char*)d_ws + needS);
    dim3 g(M_ / 128, N_ / 128, B_);
    dtw_dist_skew<<<g, dim3(256), 0, stream>>>(x, y, Dsb);
    dtw_dp3<<<dim3(B_ / 2), dim3(512), 0, stream>>>((const ushort*)Dsb, wvp);
    dtw_mul_kernel<<<dim3(mul_grid), dim3(256), 0, stream>>>(x, wvp, out);
  } else {
    dtw_dp_fused<<<dim3(B_), dim3(512), 0, stream>>>(x, y, out);
  }
}